// Round 1
// baseline (624.179 us; speedup 1.0000x reference)
//
#include <hip/hip_runtime.h>

#define T_STEPS 1024
#define BATCH   1024
#define NS      64

// Broadcast lane J (within each 32-lane group) via ds_swizzle BitMode:
// offset = or_mask<<5, and_mask=0, xor_mask=0. J must be a literal (ICE),
// hence the macro expansion instead of an unrolled loop.
#define SWZ(v, J)  __uint_as_float((unsigned)__builtin_amdgcn_ds_swizzle((int)(v), ((J) << 5)))

#define GATHER4(v, B, EB)                              \
    a0 = fmaf(e[(EB) + 0], SWZ(v, (B) + 0), a0);       \
    a1 = fmaf(e[(EB) + 1], SWZ(v, (B) + 1), a1);       \
    a2 = fmaf(e[(EB) + 2], SWZ(v, (B) + 2), a2);       \
    a3 = fmaf(e[(EB) + 3], SWZ(v, (B) + 3), a3);

// One wave per batch chain; lane s owns state s. Exp-domain recurrence:
//   u[s] <- (sum_p E[s][p] * u[p]) * exp(em_t[s]),  E = exp(trans) in 64 VGPRs.
// v5: the all-lanes broadcast of u moves from v_readlane (64 VALU->SGPR->VALU
// scalar-file round-trips per step — the suspected residual stall behind the
// ~1100 cyc/step observed at 524.5 us) to ds_swizzle_b32 broadcast patterns:
// immediate lane select, no SGPR traffic, runs on the LDS pipe and overlaps
// the v_fmac stream. ds_swizzle only reaches the lane's own 32-half, so one
// __shfl_xor(u,32) per step provides the other half and e[] is stored
// half-swapped for high lanes (e[k] = exp(trans[s][k ^ (s&32)])) so each half
// pairs its coefficients with the broadcast it actually receives.
__global__ __launch_bounds__(64)
__attribute__((amdgpu_waves_per_eu(1, 1)))
void crf_fwd_v5(const float* __restrict__ em,     // [T, B, S]
                const int*   __restrict__ seqlen, // [B]
                const float* __restrict__ start,  // [S]
                const float* __restrict__ stop,   // [S]
                const float* __restrict__ trans,  // [S, S]
                float*       __restrict__ out) {  // [B]
    const int b = blockIdx.x;
    const int s = threadIdx.x;          // 0..63
    const int L = seqlen[b];            // wave-uniform
    const int total = L - 1;            // recurrence steps

    // ---- E row for this lane, f32, pinned in VGPRs, half-swapped for the
    // high 32 lanes: e[k] = exp(trans[s][k ^ (s & 32)]). In float4 units the
    // XOR-by-32 on the element index is an XOR-by-8 on the float4 index.
    float e[NS];
    {
        const float4* t4 = reinterpret_cast<const float4*>(trans + s * NS);
        const int x8 = (s & 32) >> 2;   // 8 for high half, 0 for low half
        #pragma unroll
        for (int i = 0; i < NS / 4; ++i) {
            float4 t = t4[i ^ x8];
            e[4 * i + 0] = __expf(t.x);
            e[4 * i + 1] = __expf(t.y);
            e[4 * i + 2] = __expf(t.z);
            e[4 * i + 3] = __expf(t.w);
        }
    }
    #pragma unroll
    for (int i = 0; i < NS; ++i) asm volatile("" : "+v"(e[i]));

    // ---- init ----
    float u = __expf(start[s] + em[(size_t)b * NS + s]);
    float c = 0.f;
    const float*  gp = em + (size_t)b * NS + s;
    const size_t  TS = (size_t)BATCH * NS;

    // one step; rn=true folds a renormalization into this step's ex.
    // (step is linear in u, so scaling the output by r == scaling ex by r;
    //  the rcp/log then overlap with the gather instead of serializing.)
    auto step = [&](float ex, bool rn) {
        if (rn) {
            float m = __uint_as_float(__builtin_amdgcn_readlane(__float_as_uint(u), 0));
            m = fmaxf(m, 1e-30f);
            ex *= __builtin_amdgcn_rcpf(m);
            c += __logf(m);
        }
        const int ui = (int)__float_as_uint(u);
        const int us = __shfl_xor(ui, 32, 64);   // swapped halves of u
        float a0 = 0.f, a1 = 0.f, a2 = 0.f, a3 = 0.f;
        // p = 0..31 of this lane's (permuted) E row: broadcast from own half.
        GATHER4(ui,  0,  0)  GATHER4(ui,  4,  4)
        GATHER4(ui,  8,  8)  GATHER4(ui, 12, 12)
        GATHER4(ui, 16, 16)  GATHER4(ui, 20, 20)
        GATHER4(ui, 24, 24)  GATHER4(ui, 28, 28)
        // p = 32..63: broadcast from the swapped copy (swap latency is hidden
        // under the 32 FMAs + 32 swizzles above).
        GATHER4(us,  0, 32)  GATHER4(us,  4, 36)
        GATHER4(us,  8, 40)  GATHER4(us, 12, 44)
        GATHER4(us, 16, 48)  GATHER4(us, 20, 52)
        GATHER4(us, 24, 56)  GATHER4(us, 28, 60)
        u = ((a0 + a1) + (a2 + a3)) * ex;
    };

    // ---- main loop: unroll 8, em prefetched one group (8 steps) ahead ----
    float emq[8];
    #pragma unroll
    for (int j = 0; j < 8; ++j) {
        int t = 1 + j; if (t > T_STEPS - 1) t = T_STEPS - 1;
        emq[j] = gp[(size_t)t * TS];
    }

    int done = 0;
    while (done + 8 <= total) {
        float emn[8];
        #pragma unroll
        for (int j = 0; j < 8; ++j) {
            int t = done + 9 + j; if (t > T_STEPS - 1) t = T_STEPS - 1;
            emn[j] = gp[(size_t)t * TS];
        }
        float ex[8];
        #pragma unroll
        for (int j = 0; j < 8; ++j) ex[j] = __expf(emq[j]);

        step(ex[0], true);  step(ex[1], false); step(ex[2], false); step(ex[3], false);
        step(ex[4], true);  step(ex[5], false); step(ex[6], false); step(ex[7], false);

        #pragma unroll
        for (int j = 0; j < 8; ++j) emq[j] = emn[j];
        done += 8;
    }

    // tail: 0..7 remaining steps, em already prefetched in emq
    const int tail = total - done;
    for (int j = 0; j < tail; ++j)
        step(__expf(emq[j]), (j & 3) == 0);

    // ---- epilogue: log_Z = log(sum_s u[s]*exp(stop[s])) + c ----
    float v = u * __expf(stop[s]);
    #pragma unroll
    for (int o = 1; o < 64; o <<= 1) v += __shfl_xor(v, o, 64);
    if (s == 0) out[b] = __logf(v) + c;
}

extern "C" void kernel_launch(void* const* d_in, const int* in_sizes, int n_in,
                              void* d_out, int out_size, void* d_ws, size_t ws_size,
                              hipStream_t stream) {
    const float* em     = (const float*)d_in[0]; // [T, B, S]
    const int*   seqlen = (const int*)  d_in[1]; // [B]
    const float* start  = (const float*)d_in[2]; // [S]
    const float* stop   = (const float*)d_in[3]; // [S]
    const float* trans  = (const float*)d_in[4]; // [S, S]
    float*       out    = (float*)d_out;         // [B]

    crf_fwd_v5<<<BATCH, NS, 0, stream>>>(em, seqlen, start, stop, trans, out);
}

// Round 2
// 615.581 us; speedup vs baseline: 1.0140x; 1.0140x over previous
//
#include <hip/hip_runtime.h>

#define T_STEPS 1024
#define BATCH   1024
#define NS      64

// One wave per batch chain; lane s owns state s. Exp-domain recurrence:
//   u[s] <- (sum_p E[s][p] * u[p]) * exp(em_t[s]),  E = exp(trans) in 64 VGPRs.
//
// v6: broadcast of u across lanes via same-address LDS reads instead of 64
// ds_swizzle per step. v5's counters (VALUBusy 11%, 842 cyc/step ~= 256 DS
// instrs/CU/step * 3.3 cyc) showed the LDS pipe saturated by broadcast
// instruction COUNT (4 waves/CU share one DS pipe). Same-address ds_read is a
// hardware broadcast, so: 1x ds_write_b32 (lane s -> lds[s]) + 16x
// ds_read_b128 (wave-uniform address) = 17 DS instrs/step vs 64. Same-wave
// DS ops execute in order, so no waitcnt/barrier is needed between the write
// and the reads (one wave per block). e[] is plain exp(trans[s][k]) again.
__global__ __launch_bounds__(64)
__attribute__((amdgpu_waves_per_eu(1, 1)))
void crf_fwd_v6(const float* __restrict__ em,     // [T, B, S]
                const int*   __restrict__ seqlen, // [B]
                const float* __restrict__ start,  // [S]
                const float* __restrict__ stop,   // [S]
                const float* __restrict__ trans,  // [S, S]
                float*       __restrict__ out) {  // [B]
    __shared__ float us4[NS] __attribute__((aligned(16)));  // broadcast buffer
    const int b = blockIdx.x;
    const int s = threadIdx.x;          // 0..63
    const int L = seqlen[b];            // wave-uniform
    const int total = L - 1;            // recurrence steps

    // ---- E row for this lane, f32, pinned in VGPRs ----
    float e[NS];
    {
        const float4* t4 = reinterpret_cast<const float4*>(trans + s * NS);
        #pragma unroll
        for (int i = 0; i < NS / 4; ++i) {
            float4 t = t4[i];
            e[4 * i + 0] = __expf(t.x);
            e[4 * i + 1] = __expf(t.y);
            e[4 * i + 2] = __expf(t.z);
            e[4 * i + 3] = __expf(t.w);
        }
    }
    #pragma unroll
    for (int i = 0; i < NS; ++i) asm volatile("" : "+v"(e[i]));

    // ---- init ----
    float u = __expf(start[s] + em[(size_t)b * NS + s]);
    float c = 0.f;
    const float*  gp = em + (size_t)b * NS + s;
    const size_t  TS = (size_t)BATCH * NS;

    // one step; rn=true folds a renormalization into this step's ex.
    // (step is linear in u, so scaling the output by r == scaling ex by r;
    //  the rcp/log then overlap with the broadcast instead of serializing.)
    auto step = [&](float ex, bool rn) {
        if (rn) {
            float m = __uint_as_float(__builtin_amdgcn_readlane(__float_as_uint(u), 0));
            m = fmaxf(m, 1e-30f);
            ex *= __builtin_amdgcn_rcpf(m);
            c += __logf(m);
        }
        us4[s] = u;                       // 1x ds_write_b32
        float a0 = 0.f, a1 = 0.f, a2 = 0.f, a3 = 0.f;
        #pragma unroll
        for (int i = 0; i < NS / 4; ++i) {  // 16x ds_read_b128, wave-uniform addr
            float4 q = *reinterpret_cast<const float4*>(&us4[4 * i]);
            a0 = fmaf(e[4 * i + 0], q.x, a0);
            a1 = fmaf(e[4 * i + 1], q.y, a1);
            a2 = fmaf(e[4 * i + 2], q.z, a2);
            a3 = fmaf(e[4 * i + 3], q.w, a3);
        }
        u = ((a0 + a1) + (a2 + a3)) * ex;
    };

    // ---- main loop: unroll 8, em prefetched one group (8 steps) ahead ----
    float emq[8];
    #pragma unroll
    for (int j = 0; j < 8; ++j) {
        int t = 1 + j; if (t > T_STEPS - 1) t = T_STEPS - 1;
        emq[j] = gp[(size_t)t * TS];
    }

    int done = 0;
    while (done + 8 <= total) {
        float emn[8];
        #pragma unroll
        for (int j = 0; j < 8; ++j) {
            int t = done + 9 + j; if (t > T_STEPS - 1) t = T_STEPS - 1;
            emn[j] = gp[(size_t)t * TS];
        }
        float ex[8];
        #pragma unroll
        for (int j = 0; j < 8; ++j) ex[j] = __expf(emq[j]);

        step(ex[0], true);  step(ex[1], false); step(ex[2], false); step(ex[3], false);
        step(ex[4], true);  step(ex[5], false); step(ex[6], false); step(ex[7], false);

        #pragma unroll
        for (int j = 0; j < 8; ++j) emq[j] = emn[j];
        done += 8;
    }

    // tail: 0..7 remaining steps, em already prefetched in emq
    const int tail = total - done;
    for (int j = 0; j < tail; ++j)
        step(__expf(emq[j]), (j & 3) == 0);

    // ---- epilogue: log_Z = log(sum_s u[s]*exp(stop[s])) + c ----
    float v = u * __expf(stop[s]);
    #pragma unroll
    for (int o = 1; o < 64; o <<= 1) v += __shfl_xor(v, o, 64);
    if (s == 0) out[b] = __logf(v) + c;
}

extern "C" void kernel_launch(void* const* d_in, const int* in_sizes, int n_in,
                              void* d_out, int out_size, void* d_ws, size_t ws_size,
                              hipStream_t stream) {
    const float* em     = (const float*)d_in[0]; // [T, B, S]
    const int*   seqlen = (const int*)  d_in[1]; // [B]
    const float* start  = (const float*)d_in[2]; // [S]
    const float* stop   = (const float*)d_in[3]; // [S]
    const float* trans  = (const float*)d_in[4]; // [S, S]
    float*       out    = (float*)d_out;         // [B]

    crf_fwd_v6<<<BATCH, NS, 0, stream>>>(em, seqlen, start, stop, trans, out);
}

// Round 3
// 535.585 us; speedup vs baseline: 1.1654x; 1.1494x over previous
//
#include <hip/hip_runtime.h>

#define T_STEPS 1024
#define BATCH   1024
#define NS      64

// DPP control: rotate within 16-lane row by R (R = 1..15)
#define ROW_ROR(R) (0x120 | (R))
// ds_swizzle BitMode xor-16 within each 32-lane group:
// offset = (xor<<10)|(or<<5)|and = (16<<10)|0x1F
#define SWZ_XOR16 0x401F

// One DPP-sourced FMA: lane s reads u_q from its probed row_ror:R source lane.
#define FMA_DPP(uq, EB, R)                                                    \
    { int t_ = __builtin_amdgcn_update_dpp((int)(uq), (int)(uq),              \
                                           ROW_ROR(R), 0xF, 0xF, true);       \
      a[(R) & 3] = fmaf(__uint_as_float((unsigned)t_), e[(EB) + (R)],         \
                        a[(R) & 3]); }

// Full 16-rotation sweep of one u-copy (r=0 is the identity, no DPP needed).
#define FMA_Q(uq, EB)                                                         \
    a[0] = fmaf(__uint_as_float((unsigned)(uq)), e[(EB)], a[0]);              \
    FMA_DPP(uq, EB, 1)  FMA_DPP(uq, EB, 2)  FMA_DPP(uq, EB, 3)                \
    FMA_DPP(uq, EB, 4)  FMA_DPP(uq, EB, 5)  FMA_DPP(uq, EB, 6)                \
    FMA_DPP(uq, EB, 7)  FMA_DPP(uq, EB, 8)  FMA_DPP(uq, EB, 9)                \
    FMA_DPP(uq, EB, 10) FMA_DPP(uq, EB, 11) FMA_DPP(uq, EB, 12)               \
    FMA_DPP(uq, EB, 13) FMA_DPP(uq, EB, 14) FMA_DPP(uq, EB, 15)

#define PROBE(R) d[R] = __builtin_amdgcn_update_dpp(s, s, ROW_ROR(R), 0xF, 0xF, true);

// One wave per batch chain; lane s owns state s. Exp-domain recurrence:
//   u[s] <- (sum_p E[s][p] * u[p]) * exp(em_t[s]),  E = exp(trans) in 64 VGPRs.
//
// v7: v6's counters showed the LDS BROADCAST is return-bandwidth-bound, not
// instruction-bound (17 DS instr/step ~= same 823 cyc/step as 64: wave-uniform
// ds_read_b128 still moves 64 lanes x 16 B = 1 KB/instr through the return
// bus; 4 waves/CU * 16 KB/step at ~85 B/cyc ~= the whole step time). So the
// broadcast moves OFF the DS pipe onto the VALU's DPP permute network:
//   - 3 XOR copies of u (xor16 via ds_swizzle, xor32/xor48 via shfl_xor):
//     the only DS work left, ~0.75 KB/step vs 16 KB.
//   - per copy q: 15x v_mov_b32 dpp row_ror:r + 16 fmac; (q,r) enumerates all
//     64 source lanes exactly once. E is laid out per-lane to match.
// The prologue PROBES the actual row_ror source mapping (DPP on the lane-id
// vector), so the E layout is correct under either rotation direction.
__global__ __launch_bounds__(64)
__attribute__((amdgpu_waves_per_eu(1, 1)))
void crf_fwd_v7(const float* __restrict__ em,     // [T, B, S]
                const int*   __restrict__ seqlen, // [B]
                const float* __restrict__ start,  // [S]
                const float* __restrict__ stop,   // [S]
                const float* __restrict__ trans,  // [S, S]
                float*       __restrict__ out) {  // [B]
    const int b = blockIdx.x;
    const int s = threadIdx.x;          // 0..63
    const int L = seqlen[b];            // wave-uniform
    const int total = L - 1;            // recurrence steps

    // ---- probe DPP row_ror source lanes, then build the matched E layout:
    // u_q[lane j] = u[j ^ (q<<4)]; DPP(row_ror:r) hands lane s the value from
    // lane d[r], i.e. u[d[r] ^ (q<<4)] -> coefficient e[q*16+r] = E[s][d[r]^(q<<4)].
    float e[NS];
    {
        int d[16];
        d[0] = s;
        PROBE(1)  PROBE(2)  PROBE(3)  PROBE(4)  PROBE(5)
        PROBE(6)  PROBE(7)  PROBE(8)  PROBE(9)  PROBE(10)
        PROBE(11) PROBE(12) PROBE(13) PROBE(14) PROBE(15)
        const float* tr = trans + s * NS;
        #pragma unroll
        for (int q = 0; q < 4; ++q)
            #pragma unroll
            for (int r = 0; r < 16; ++r)
                e[q * 16 + r] = __expf(tr[d[r] ^ (q << 4)]);
    }
    #pragma unroll
    for (int i = 0; i < NS; ++i) asm volatile("" : "+v"(e[i]));

    // ---- init ----
    float u = __expf(start[s] + em[(size_t)b * NS + s]);
    float c = 0.f;
    const float*  gp = em + (size_t)b * NS + s;
    const size_t  TS = (size_t)BATCH * NS;

    // one step; rn=true folds a renormalization into this step's ex.
    // (step is linear in u, so scaling the output by r == scaling ex by r;
    //  the rcp/log then overlap with the gather instead of serializing.)
    auto step = [&](float ex, bool rn) {
        if (rn) {
            float m = __uint_as_float(__builtin_amdgcn_readlane(__float_as_uint(u), 0));
            m = fmaxf(m, 1e-30f);
            ex *= __builtin_amdgcn_rcpf(m);
            c += __logf(m);
        }
        const int u0 = (int)__float_as_uint(u);
        const int u1 = __builtin_amdgcn_ds_swizzle(u0, SWZ_XOR16); // u[j^16]
        const int u2 = __shfl_xor(u0, 32, 64);                     // u[j^32]
        const int u3 = __shfl_xor(u1, 32, 64);                     // u[j^48]
        float a[4] = {0.f, 0.f, 0.f, 0.f};
        FMA_Q(u0,  0)
        FMA_Q(u1, 16)
        FMA_Q(u2, 32)
        FMA_Q(u3, 48)
        u = ((a[0] + a[1]) + (a[2] + a[3])) * ex;
    };

    // ---- main loop: unroll 8, em prefetched one group (8 steps) ahead ----
    float emq[8];
    #pragma unroll
    for (int j = 0; j < 8; ++j) {
        int t = 1 + j; if (t > T_STEPS - 1) t = T_STEPS - 1;
        emq[j] = gp[(size_t)t * TS];
    }

    int done = 0;
    while (done + 8 <= total) {
        float emn[8];
        #pragma unroll
        for (int j = 0; j < 8; ++j) {
            int t = done + 9 + j; if (t > T_STEPS - 1) t = T_STEPS - 1;
            emn[j] = gp[(size_t)t * TS];
        }
        float ex[8];
        #pragma unroll
        for (int j = 0; j < 8; ++j) ex[j] = __expf(emq[j]);

        step(ex[0], true);  step(ex[1], false); step(ex[2], false); step(ex[3], false);
        step(ex[4], true);  step(ex[5], false); step(ex[6], false); step(ex[7], false);

        #pragma unroll
        for (int j = 0; j < 8; ++j) emq[j] = emn[j];
        done += 8;
    }

    // tail: 0..7 remaining steps, em already prefetched in emq
    const int tail = total - done;
    for (int j = 0; j < tail; ++j)
        step(__expf(emq[j]), (j & 3) == 0);

    // ---- epilogue: log_Z = log(sum_s u[s]*exp(stop[s])) + c ----
    float v = u * __expf(stop[s]);
    #pragma unroll
    for (int o = 1; o < 64; o <<= 1) v += __shfl_xor(v, o, 64);
    if (s == 0) out[b] = __logf(v) + c;
}

extern "C" void kernel_launch(void* const* d_in, const int* in_sizes, int n_in,
                              void* d_out, int out_size, void* d_ws, size_t ws_size,
                              hipStream_t stream) {
    const float* em     = (const float*)d_in[0]; // [T, B, S]
    const int*   seqlen = (const int*)  d_in[1]; // [B]
    const float* start  = (const float*)d_in[2]; // [S]
    const float* stop   = (const float*)d_in[3]; // [S]
    const float* trans  = (const float*)d_in[4]; // [S, S]
    float*       out    = (float*)d_out;         // [B]

    crf_fwd_v7<<<BATCH, NS, 0, stream>>>(em, seqlen, start, stop, trans, out);
}

// Round 4
// 534.838 us; speedup vs baseline: 1.1670x; 1.0014x over previous
//
#include <hip/hip_runtime.h>

#define T_STEPS 1024
#define BATCH   1024
#define NS      64

// DPP control: rotate within 16-lane row by R (R = 1..15)
#define ROW_ROR(R) (0x120 | (R))
// ds_swizzle BitMode xor-16 within each 32-lane group:
// offset = (xor<<10)|(or<<5)|and = (16<<10)|0x1F
#define SWZ_XOR16 0x401F

// VALU half-swap (gfx950): exchanges a.hi31..32 with b.lo lanes between the
// two registers. Direction/placement is NOT assumed anywhere — the prologue
// probes the full composed lane mapping, so any consistent semantic works.
#define PERMLANE32_SWAP(a, b) \
    asm("v_permlane32_swap_b32 %0, %1" : "+v"(a), "+v"(b))

// One DPP-sourced FMA: lane s reads uq from its probed row_ror:R source lane.
#define FMA_DPP(uq, EB, R)                                                    \
    { int t_ = __builtin_amdgcn_update_dpp((int)(uq), (int)(uq),              \
                                           ROW_ROR(R), 0xF, 0xF, true);       \
      a[(R) & 3] = fmaf(__uint_as_float((unsigned)t_), e[(EB) + (R)],         \
                        a[(R) & 3]); }

// Full 16-rotation sweep of one u-copy (r=0 is the identity, no DPP needed).
#define FMA_Q(uq, EB)                                                         \
    a[0] = fmaf(__uint_as_float((unsigned)(uq)), e[(EB)], a[0]);              \
    FMA_DPP(uq, EB, 1)  FMA_DPP(uq, EB, 2)  FMA_DPP(uq, EB, 3)                \
    FMA_DPP(uq, EB, 4)  FMA_DPP(uq, EB, 5)  FMA_DPP(uq, EB, 6)                \
    FMA_DPP(uq, EB, 7)  FMA_DPP(uq, EB, 8)  FMA_DPP(uq, EB, 9)                \
    FMA_DPP(uq, EB, 10) FMA_DPP(uq, EB, 11) FMA_DPP(uq, EB, 12)               \
    FMA_DPP(uq, EB, 13) FMA_DPP(uq, EB, 14) FMA_DPP(uq, EB, 15)

#define PROBE_R(dst, src, R)                                                  \
    dst[R] = __builtin_amdgcn_update_dpp((int)(src), (int)(src),              \
                                         ROW_ROR(R), 0xF, 0xF, true);
#define PROBE16(dst, src)                                                     \
    dst[0] = (src);                                                           \
    PROBE_R(dst, src, 1)  PROBE_R(dst, src, 2)  PROBE_R(dst, src, 3)          \
    PROBE_R(dst, src, 4)  PROBE_R(dst, src, 5)  PROBE_R(dst, src, 6)          \
    PROBE_R(dst, src, 7)  PROBE_R(dst, src, 8)  PROBE_R(dst, src, 9)          \
    PROBE_R(dst, src, 10) PROBE_R(dst, src, 11) PROBE_R(dst, src, 12)         \
    PROBE_R(dst, src, 13) PROBE_R(dst, src, 14) PROBE_R(dst, src, 15)

// One wave per batch chain; lane s owns state s. Exp-domain recurrence:
//   u[s] <- (sum_p E[s][p] * u[p]) * exp(em_t[s]),  E = exp(trans) in 64 VGPRs.
//
// v8: v7's residual (~626 cyc/step vs ~155-270 issue) is attributed to the
// per-step DS-pipe chain: ds_swizzle + shfl_xor + DEPENDENT shfl_xor(shfl) =
// two serialized DS round-trips (~25-120 cyc each, fully exposed at 1
// wave/SIMD). v8 builds the four row-replicated u-copies with 2x
// v_permlane32_swap_b32 (VALU, ~4 cyc) + 1x ds_swizzle xor16 whose latency
// hides under the first 64 FMAs (its consumers are quarters C/D, last).
// The prologue probes the COMPOSED lane mapping (swizzle -> permlane ->
// row_ror) on the lane-id vector, so e[] matches hardware semantics exactly
// regardless of swap/rotation direction.
__global__ __launch_bounds__(64)
__attribute__((amdgpu_waves_per_eu(1, 1)))
void crf_fwd_v8(const float* __restrict__ em,     // [T, B, S]
                const int*   __restrict__ seqlen, // [B]
                const float* __restrict__ start,  // [S]
                const float* __restrict__ stop,   // [S]
                const float* __restrict__ trans,  // [S, S]
                float*       __restrict__ out) {  // [B]
    const int b = blockIdx.x;
    const int s = threadIdx.x;          // 0..63
    const int L = seqlen[b];            // wave-uniform
    const int total = L - 1;            // recurrence steps

    // ---- probe composed source-lane maps, build matched E layout ----
    float e[NS];
    {
        int ia = s, ib = s;
        PERMLANE32_SWAP(ia, ib);                              // halves of id
        int ix = __builtin_amdgcn_ds_swizzle(s, SWZ_XOR16);   // s^16
        int ic = ix, id_ = ix;
        PERMLANE32_SWAP(ic, id_);
        int pA[16], pB[16], pC[16], pD[16];
        PROBE16(pA, ia)  PROBE16(pB, ib)  PROBE16(pC, ic)  PROBE16(pD, id_)
        const float* tr = trans + s * NS;
        #pragma unroll
        for (int r = 0; r < 16; ++r) {
            e[ 0 + r] = __expf(tr[pA[r]]);
            e[16 + r] = __expf(tr[pB[r]]);
            e[32 + r] = __expf(tr[pC[r]]);
            e[48 + r] = __expf(tr[pD[r]]);
        }
    }
    #pragma unroll
    for (int i = 0; i < NS; ++i) asm volatile("" : "+v"(e[i]));

    // ---- init ----
    float u = __expf(start[s] + em[(size_t)b * NS + s]);
    float c = 0.f;
    const float*  gp = em + (size_t)b * NS + s;
    const size_t  TS = (size_t)BATCH * NS;

    // one step; rn=true folds a renormalization into this step's ex.
    // (step is linear in u, so scaling the output by r == scaling ex by r;
    //  the rcp/log then overlap with the gather instead of serializing.)
    auto step = [&](float ex, bool rn) {
        if (rn) {
            float m = __uint_as_float(__builtin_amdgcn_readlane(__float_as_uint(u), 0));
            m = fmaxf(m, 1e-30f);
            ex *= __builtin_amdgcn_rcpf(m);
            c += __logf(m);
        }
        const int ui = (int)__float_as_uint(u);
        int u1 = __builtin_amdgcn_ds_swizzle(ui, SWZ_XOR16);  // issue DS early
        int pa = ui, pb = ui;
        PERMLANE32_SWAP(pa, pb);                               // VALU
        float a[4] = {0.f, 0.f, 0.f, 0.f};
        FMA_Q(pa,  0)
        FMA_Q(pb, 16)
        int pc = u1, pd = u1;                                  // DS latency hidden
        PERMLANE32_SWAP(pc, pd);
        FMA_Q(pc, 32)
        FMA_Q(pd, 48)
        u = ((a[0] + a[1]) + (a[2] + a[3])) * ex;
    };

    // ---- main loop: unroll 8, em prefetched one group (8 steps) ahead ----
    float emq[8];
    #pragma unroll
    for (int j = 0; j < 8; ++j) {
        int t = 1 + j; if (t > T_STEPS - 1) t = T_STEPS - 1;
        emq[j] = gp[(size_t)t * TS];
    }

    int done = 0;
    while (done + 8 <= total) {
        float emn[8];
        #pragma unroll
        for (int j = 0; j < 8; ++j) {
            int t = done + 9 + j; if (t > T_STEPS - 1) t = T_STEPS - 1;
            emn[j] = gp[(size_t)t * TS];
        }
        float ex[8];
        #pragma unroll
        for (int j = 0; j < 8; ++j) ex[j] = __expf(emq[j]);

        step(ex[0], true);  step(ex[1], false); step(ex[2], false); step(ex[3], false);
        step(ex[4], true);  step(ex[5], false); step(ex[6], false); step(ex[7], false);

        #pragma unroll
        for (int j = 0; j < 8; ++j) emq[j] = emn[j];
        done += 8;
    }

    // tail: 0..7 remaining steps, em already prefetched in emq
    const int tail = total - done;
    for (int j = 0; j < tail; ++j)
        step(__expf(emq[j]), (j & 3) == 0);

    // ---- epilogue: log_Z = log(sum_s u[s]*exp(stop[s])) + c ----
    float v = u * __expf(stop[s]);
    #pragma unroll
    for (int o = 1; o < 64; o <<= 1) v += __shfl_xor(v, o, 64);
    if (s == 0) out[b] = __logf(v) + c;
}

extern "C" void kernel_launch(void* const* d_in, const int* in_sizes, int n_in,
                              void* d_out, int out_size, void* d_ws, size_t ws_size,
                              hipStream_t stream) {
    const float* em     = (const float*)d_in[0]; // [T, B, S]
    const int*   seqlen = (const int*)  d_in[1]; // [B]
    const float* start  = (const float*)d_in[2]; // [S]
    const float* stop   = (const float*)d_in[3]; // [S]
    const float* trans  = (const float*)d_in[4]; // [S, S]
    float*       out    = (float*)d_out;         // [B]

    crf_fwd_v8<<<BATCH, NS, 0, stream>>>(em, seqlen, start, stop, trans, out);
}